// Round 1
// baseline (199.567 us; speedup 1.0000x reference)
//
#include <hip/hip_runtime.h>

#define IN_DIM 64
#define HID 24
#define EH 20
#define NE 3
#define GH 16
#define OUT_D 3
#define LN_EPS 1e-5f

__device__ __forceinline__ float fexp(float v) {
    // e^v via v_exp_f32 (2^x)
    return __builtin_amdgcn_exp2f(v * 1.44269504088896340736f);
}
__device__ __forceinline__ float frcp(float v) { return __builtin_amdgcn_rcpf(v); }
__device__ __forceinline__ float silu_f(float v) { return v * frcp(1.0f + fexp(-v)); }
__device__ __forceinline__ float tanh_f(float v) {
    // tanh(x) = 2/(1+e^{-2x}) - 1 ; saturates correctly via exp->inf->rcp->0
    return 2.0f * frcp(1.0f + fexp(-2.0f * v)) - 1.0f;
}

__global__ __launch_bounds__(256) void moe_fused_kernel(
    const float* __restrict__ x,
    const float* __restrict__ W1,  const float* __restrict__ b1,
    const float* __restrict__ lng, const float* __restrict__ lnb,
    const float* __restrict__ W2,  const float* __restrict__ b2,
    const float* __restrict__ Wg1, const float* __restrict__ bg1,
    const float* __restrict__ Wg2, const float* __restrict__ bg2,
    const float* __restrict__ We1, const float* __restrict__ be1,
    const float* __restrict__ We2, const float* __restrict__ be2,
    const float* __restrict__ Wh,  const float* __restrict__ bh,
    const float* __restrict__ osc,
    float* __restrict__ out, int B)
{
    const int row = blockIdx.x * 256 + threadIdx.x;
    if (row >= B) return;

    const float4* xr = (const float4*)(x + (size_t)row * IN_DIM);

    // ---- stage 1: x -> {h1[24], gate_pre[16], lin[3]} in one streaming pass ----
    float h1[HID];
    float g1[GH];
    float lin[OUT_D];
#pragma unroll
    for (int j = 0; j < HID; ++j) h1[j] = b1[j];
#pragma unroll
    for (int j = 0; j < GH; ++j) g1[j] = bg1[j];
#pragma unroll
    for (int j = 0; j < OUT_D; ++j) lin[j] = bh[j];

#pragma unroll 4
    for (int c = 0; c < IN_DIM / 4; ++c) {
        float4 v = xr[c];
        float xv[4] = {v.x, v.y, v.z, v.w};
#pragma unroll
        for (int u = 0; u < 4; ++u) {
            const int k = c * 4 + u;
            const float xk = xv[u];
#pragma unroll
            for (int j = 0; j < HID; ++j)
                h1[j] = __builtin_fmaf(xk, W1[k * HID + j], h1[j]);
#pragma unroll
            for (int j = 0; j < GH; ++j)
                g1[j] = __builtin_fmaf(xk, Wg1[k * GH + j], g1[j]);
#pragma unroll
            for (int j = 0; j < OUT_D; ++j)
                lin[j] = __builtin_fmaf(xk, Wh[k * OUT_D + j], lin[j]);
        }
    }

    // ---- silu + layernorm on h1 ----
#pragma unroll
    for (int j = 0; j < HID; ++j) h1[j] = silu_f(h1[j]);

    float mu = 0.0f;
#pragma unroll
    for (int j = 0; j < HID; ++j) mu += h1[j];
    mu *= (1.0f / HID);
    float var = 0.0f;
#pragma unroll
    for (int j = 0; j < HID; ++j) { float d = h1[j] - mu; var = __builtin_fmaf(d, d, var); }
    var *= (1.0f / HID);
    const float inv = __builtin_amdgcn_rsqf(var + LN_EPS);
#pragma unroll
    for (int j = 0; j < HID; ++j)
        h1[j] = (h1[j] - mu) * inv * lng[j] + lnb[j];

    // ---- stage 2: h2 = silu(h1 @ W2 + b2) ----
    float h2[HID];
#pragma unroll
    for (int j = 0; j < HID; ++j) h2[j] = b2[j];
#pragma unroll
    for (int k = 0; k < HID; ++k) {
        const float hk = h1[k];
#pragma unroll
        for (int j = 0; j < HID; ++j)
            h2[j] = __builtin_fmaf(hk, W2[k * HID + j], h2[j]);
    }
#pragma unroll
    for (int j = 0; j < HID; ++j) h2[j] = silu_f(h2[j]);

    // ---- gate: softmax(tanh(g1) @ Wg2 + bg2) ----
    float lg[NE];
#pragma unroll
    for (int o = 0; o < NE; ++o) lg[o] = bg2[o];
#pragma unroll
    for (int k = 0; k < GH; ++k) {
        const float tk = tanh_f(g1[k]);
#pragma unroll
        for (int o = 0; o < NE; ++o)
            lg[o] = __builtin_fmaf(tk, Wg2[k * NE + o], lg[o]);
    }
    float m = fmaxf(lg[0], fmaxf(lg[1], lg[2]));
    float e0 = fexp(lg[0] - m), e1 = fexp(lg[1] - m), e2 = fexp(lg[2] - m);
    const float rs = frcp(e0 + e1 + e2);
    float gw[NE] = {e0 * rs, e1 * rs, e2 * rs};

    // ---- experts ----
    float moe[OUT_D] = {0.0f, 0.0f, 0.0f};
#pragma unroll
    for (int e = 0; e < NE; ++e) {
        float eh[EH];
#pragma unroll
        for (int j = 0; j < EH; ++j) eh[j] = be1[e * EH + j];
#pragma unroll
        for (int k = 0; k < HID; ++k) {
            const float hk = h2[k];
#pragma unroll
            for (int j = 0; j < EH; ++j)
                eh[j] = __builtin_fmaf(hk, We1[(e * HID + k) * EH + j], eh[j]);
        }
#pragma unroll
        for (int j = 0; j < EH; ++j) eh[j] = silu_f(eh[j]);

        float eo[OUT_D];
#pragma unroll
        for (int o = 0; o < OUT_D; ++o) eo[o] = be2[e * OUT_D + o];
#pragma unroll
        for (int k = 0; k < EH; ++k) {
            const float ek = eh[k];
#pragma unroll
            for (int o = 0; o < OUT_D; ++o)
                eo[o] = __builtin_fmaf(ek, We2[(e * EH + k) * OUT_D + o], eo[o]);
        }
#pragma unroll
        for (int o = 0; o < OUT_D; ++o)
            moe[o] = __builtin_fmaf(gw[e], eo[o], moe[o]);
    }

    // ---- output: lin (has bh) + moe * out_scale ----
    float* op = out + (size_t)row * OUT_D;
#pragma unroll
    for (int o = 0; o < OUT_D; ++o)
        op[o] = __builtin_fmaf(moe[o], osc[o], lin[o]);
}

extern "C" void kernel_launch(void* const* d_in, const int* in_sizes, int n_in,
                              void* d_out, int out_size, void* d_ws, size_t ws_size,
                              hipStream_t stream) {
    const float* x   = (const float*)d_in[0];
    const float* W1  = (const float*)d_in[1];
    const float* b1  = (const float*)d_in[2];
    const float* lng = (const float*)d_in[3];
    const float* lnb = (const float*)d_in[4];
    const float* W2  = (const float*)d_in[5];
    const float* b2  = (const float*)d_in[6];
    const float* Wg1 = (const float*)d_in[7];
    const float* bg1 = (const float*)d_in[8];
    const float* Wg2 = (const float*)d_in[9];
    const float* bg2 = (const float*)d_in[10];
    const float* We1 = (const float*)d_in[11];
    const float* be1 = (const float*)d_in[12];
    const float* We2 = (const float*)d_in[13];
    const float* be2 = (const float*)d_in[14];
    const float* Wh  = (const float*)d_in[15];
    const float* bh  = (const float*)d_in[16];
    const float* osc = (const float*)d_in[17];
    float* out = (float*)d_out;

    const int B = in_sizes[0] / IN_DIM;
    dim3 grid((B + 255) / 256);
    moe_fused_kernel<<<grid, 256, 0, stream>>>(
        x, W1, b1, lng, lnb, W2, b2, Wg1, bg1, Wg2, bg2,
        We1, be1, We2, be2, Wh, bh, osc, out, B);
}

// Round 2
// 198.042 us; speedup vs baseline: 1.0077x; 1.0077x over previous
//
#include <hip/hip_runtime.h>

typedef __attribute__((ext_vector_type(8))) short short8;
typedef __attribute__((ext_vector_type(4))) float f32x4;

#define LOG2E 1.44269504088896340736f

__device__ __forceinline__ float fexp2(float v) { return __builtin_amdgcn_exp2f(v); }
__device__ __forceinline__ float frcp(float v)  { return __builtin_amdgcn_rcpf(v); }
__device__ __forceinline__ float silu_f(float v){ return v * frcp(1.0f + fexp2(-v * LOG2E)); }
__device__ __forceinline__ float tanh_f(float v){ return 2.0f * frcp(1.0f + fexp2(-2.0f * LOG2E * v)) - 1.0f; }

__device__ __forceinline__ unsigned short f2bf(float f) {
    unsigned int u = __float_as_uint(f);
    u = (u + 0x7FFFu + ((u >> 16) & 1u)) >> 16;   // round-to-nearest-even
    return (unsigned short)u;
}
__device__ __forceinline__ unsigned int pack2(float lo, float hi) {
    return (unsigned int)f2bf(lo) | ((unsigned int)f2bf(hi) << 16);
}
__device__ __forceinline__ void lds_fence() {
    asm volatile("s_waitcnt lgkmcnt(0)" ::: "memory");
}
#define MFMA16(a, b, cc) __builtin_amdgcn_mfma_f32_16x16x32_bf16(a, b, cc, 0, 0, 0)

// Feature concat for stage 1: f in [0,24)=h1(W1), [24,40)=gate(Wg1), [40,43)=lin(Wh), [43,48)=pad
// MFMA roles: A = weights^T (M=features, K=in), B = x (K=in, N=16 batch rows)
// A frag: lane holds m=lane&15, k=8*(lane>>4)+e ; B frag: n=lane&15, k=8*(lane>>4)+e
// C frag: n(batch)=lane&15, m(feature)=4*(lane>>4)+reg

__global__ __launch_bounds__(256) void moe_mfma_kernel(
    const float* __restrict__ x,
    const float* __restrict__ W1,  const float* __restrict__ b1,
    const float* __restrict__ lng, const float* __restrict__ lnb,
    const float* __restrict__ W2,  const float* __restrict__ b2,
    const float* __restrict__ Wg1, const float* __restrict__ bg1,
    const float* __restrict__ Wg2, const float* __restrict__ bg2,
    const float* __restrict__ We1, const float* __restrict__ be1,
    const float* __restrict__ We2, const float* __restrict__ be2,
    const float* __restrict__ Wh,  const float* __restrict__ bh,
    const float* __restrict__ osc,
    float* __restrict__ out, int B)
{
    // per-wave scratch; strides chosen for 16B-aligned ds_read_b128 and <=2-way banks
    __shared__ unsigned short Hb[4][16][40];  // h (stage2 B) then h2 (expert B): k 0..31
    __shared__ unsigned short Gb[4][16][40];  // tanh(g1) (gate B): k 0..31
    __shared__ unsigned short Eb[4][16][72];  // expert hidden concat: k 0..63
    __shared__ float          Fb[4][16][20];  // final gather: 0-8 eo, 9-11 logits, 12-14 lin

    const int tid  = threadIdx.x;
    const int w    = tid >> 6;
    const int lane = tid & 63;
    const int c    = lane & 15;   // batch row within 16-row group
    const int g    = lane >> 4;   // lane group 0..3

    // ================= one-time init: A fragments + biases =================
    // stage1: Wcat = [W1 | Wg1 | Wh] -> A[m][k] = Wcat[k][m]
    short8 a1[3][2];
#pragma unroll
    for (int t = 0; t < 3; ++t) {
        const int f = 16 * t + c;
#pragma unroll
        for (int s = 0; s < 2; ++s) {
#pragma unroll
            for (int e = 0; e < 8; ++e) {
                const int k = 32 * s + 8 * g + e;
                float v = 0.0f;
                if (f < 24)      v = W1[k * 24 + f];
                else if (f < 40) v = Wg1[k * 16 + (f - 24)];
                else if (f < 43) v = Wh[k * 3 + (f - 40)];
                a1[t][s][e] = (short)f2bf(v);
            }
        }
    }
    // W2 with LN gain folded: A[m][k] = lng[k]*W2[k][m], K pad 24->32
    short8 aw[2];
#pragma unroll
    for (int t = 0; t < 2; ++t) {
        const int m = 16 * t + c;
#pragma unroll
        for (int e = 0; e < 8; ++e) {
            const int k = 8 * g + e;
            float v = (m < 24 && k < 24) ? lng[k] * W2[k * 24 + m] : 0.0f;
            aw[t][e] = (short)f2bf(v);
        }
    }
    // Expert hidden concat: m = 20*e + j in [0,60): A[m][k] = We1[e][k][j]
    short8 ae[4];
#pragma unroll
    for (int t = 0; t < 4; ++t) {
        const int m  = 16 * t + c;
        const int mc = (m < 60) ? m : 0;
        const int ei = mc / 20, j = mc % 20;
#pragma unroll
        for (int e = 0; e < 8; ++e) {
            const int k = 8 * g + e;
            float v = (m < 60 && k < 24) ? We1[(ei * 24 + k) * 20 + j] : 0.0f;
            ae[t][e] = (short)f2bf(v);
        }
    }
    // We2 block-diag (osc folded): m = 3*e + o in [0,9); k in [0,60): block e owns k in [20e,20e+20)
    short8 ao[2];
    {
        const int m  = c;
        const int mc = (m < 9) ? m : 0;
        const int ei = mc / 3, o = mc % 3;
        const float oscv = osc[o];
#pragma unroll
        for (int s = 0; s < 2; ++s) {
#pragma unroll
            for (int e = 0; e < 8; ++e) {
                const int k  = 32 * s + 8 * g + e;
                const int ke = k - 20 * ei;
                const int kec = (ke >= 0 && ke < 20) ? ke : 0;
                float v = (m < 9 && ke >= 0 && ke < 20) ? We2[(ei * 20 + kec) * 3 + o] * oscv : 0.0f;
                ao[s][e] = (short)f2bf(v);
            }
        }
    }
    // gate: A[m][k] = Wg2[k][m], K pad 16->32
    short8 ag;
#pragma unroll
    for (int e = 0; e < 8; ++e) {
        const int k = 8 * g + e;
        float v = (c < 3 && k < 16) ? Wg2[k * 3 + c] : 0.0f;
        ag[e] = (short)f2bf(v);
    }

    // biases (C-init values), feature m = 16t + 4g + r
    float bs1[3][4];
#pragma unroll
    for (int t = 0; t < 3; ++t)
#pragma unroll
    for (int r = 0; r < 4; ++r) {
        const int m = 16 * t + 4 * g + r;
        float v = 0.0f;
        if (m < 24)      v = b1[m];
        else if (m < 40) v = bg1[m - 24];
        else if (m < 43) v = bh[m - 40];
        bs1[t][r] = v;
    }
    // b2' = b2 + lnb @ W2 (LN beta fold)
    float bs2[2][4];
#pragma unroll
    for (int t = 0; t < 2; ++t)
#pragma unroll
    for (int r = 0; r < 4; ++r) {
        const int m = 16 * t + 4 * g + r;
        float v = 0.0f;
        if (m < 24) {
            v = b2[m];
            for (int k = 0; k < 24; ++k) v += lnb[k] * W2[k * 24 + m];
        }
        bs2[t][r] = v;
    }
    float bse[4][4];
#pragma unroll
    for (int t = 0; t < 4; ++t)
#pragma unroll
    for (int r = 0; r < 4; ++r) {
        const int m = 16 * t + 4 * g + r;
        bse[t][r] = (m < 60) ? be1[m] : 0.0f;   // be1 flat [3*20]
    }
    float bso[4], bsg[4];
#pragma unroll
    for (int r = 0; r < 4; ++r) {
        const int m = 4 * g + r;
        bso[r] = (m < 9) ? be2[m] * osc[m % 3] : 0.0f;  // be2 flat [3*3], osc folded
        bsg[r] = (m < 3) ? bg2[m] : 0.0f;
    }

    // one-time zero pads in LDS (persist across groups)
    *(unsigned int*)&Gb[w][c][16 + 4 * g]     = 0u;
    *(unsigned int*)&Gb[w][c][16 + 4 * g + 2] = 0u;
    if (g >= 2) {
        *(unsigned int*)&Hb[w][c][24 + 4 * (g - 2)]     = 0u;
        *(unsigned int*)&Hb[w][c][24 + 4 * (g - 2) + 2] = 0u;
    }

    // ================= main grid-stride loop =================
    const long long rows_per_pass = (long long)gridDim.x * 256LL;
    for (long long base = (long long)blockIdx.x * 256LL; base < B; base += rows_per_pass) {
#pragma unroll 1
        for (int q = 0; q < 4; ++q) {
            const long long row = base + w * 64 + q * 16 + c;
            const float* xr = x + row * 64;

            // B fragments of x: lane reads x[row][32s+8g .. +8]
            short8 bx[2];
#pragma unroll
            for (int s = 0; s < 2; ++s) {
                const float4 p0 = *(const float4*)(xr + 32 * s + 8 * g);
                const float4 p1 = *(const float4*)(xr + 32 * s + 8 * g + 4);
                bx[s][0] = (short)f2bf(p0.x); bx[s][1] = (short)f2bf(p0.y);
                bx[s][2] = (short)f2bf(p0.z); bx[s][3] = (short)f2bf(p0.w);
                bx[s][4] = (short)f2bf(p1.x); bx[s][5] = (short)f2bf(p1.y);
                bx[s][6] = (short)f2bf(p1.z); bx[s][7] = (short)f2bf(p1.w);
            }

            // ---- stage 1: 3 M-tiles x 2 K-steps ----
            f32x4 c0, c1, c2;
#pragma unroll
            for (int r = 0; r < 4; ++r) { c0[r] = bs1[0][r]; c1[r] = bs1[1][r]; c2[r] = bs1[2][r]; }
            c0 = MFMA16(a1[0][0], bx[0], c0); c0 = MFMA16(a1[0][1], bx[1], c0);
            c1 = MFMA16(a1[1][0], bx[0], c1); c1 = MFMA16(a1[1][1], bx[1], c1);
            c2 = MFMA16(a1[2][0], bx[0], c2); c2 = MFMA16(a1[2][1], bx[1], c2);

            // ---- gate: tanh -> LDS -> MFMA ----
            float gA[4], gB[4];
#pragma unroll
            for (int r = 0; r < 4; ++r) { gA[r] = tanh_f(c1[r]); gB[r] = tanh_f(c2[r]); }
            lds_fence();
            if (g >= 2) {  // gate feats 0-7 come from tile1 groups 2,3
                *(unsigned int*)&Gb[w][c][4 * (g - 2)]     = pack2(gA[0], gA[1]);
                *(unsigned int*)&Gb[w][c][4 * (g - 2) + 2] = pack2(gA[2], gA[3]);
            } else {       // gate feats 8-15 come from tile2 groups 0,1
                *(unsigned int*)&Gb[w][c][8 + 4 * g]     = pack2(gB[0], gB[1]);
                *(unsigned int*)&Gb[w][c][8 + 4 * g + 2] = pack2(gB[2], gB[3]);
            }
            lds_fence();
            const short8 bgf = *(const short8*)&Gb[w][c][8 * g];
            f32x4 cg;
#pragma unroll
            for (int r = 0; r < 4; ++r) cg[r] = bsg[r];
            cg = MFMA16(ag, bgf, cg);   // logits at g==0, reg 0..2

            // ---- silu + LayerNorm (gain/beta folded into W2/b2') ----
            float h0[4], h1v[4];
#pragma unroll
            for (int r = 0; r < 4; ++r) { h0[r] = silu_f(c0[r]); h1v[r] = silu_f(c1[r]); }
            float S = h0[0] + h0[1] + h0[2] + h0[3];
            float Q = h0[0]*h0[0] + h0[1]*h0[1] + h0[2]*h0[2] + h0[3]*h0[3];
            if (g < 2) {
                S += h1v[0] + h1v[1] + h1v[2] + h1v[3];
                Q += h1v[0]*h1v[0] + h1v[1]*h1v[1] + h1v[2]*h1v[2] + h1v[3]*h1v[3];
            }
            S += __shfl_xor(S, 16, 64); S += __shfl_xor(S, 32, 64);
            Q += __shfl_xor(Q, 16, 64); Q += __shfl_xor(Q, 32, 64);
            const float mu  = S * (1.0f / 24.0f);
            float var = Q * (1.0f / 24.0f) - mu * mu;
            var = fmaxf(var, 0.0f);
            const float inv = __builtin_amdgcn_rsqf(var + 1e-5f);

            lds_fence();
            *(unsigned int*)&Hb[w][c][4 * g]     = pack2((h0[0]-mu)*inv, (h0[1]-mu)*inv);
            *(unsigned int*)&Hb[w][c][4 * g + 2] = pack2((h0[2]-mu)*inv, (h0[3]-mu)*inv);
            if (g < 2) {
                *(unsigned int*)&Hb[w][c][16 + 4 * g]     = pack2((h1v[0]-mu)*inv, (h1v[1]-mu)*inv);
                *(unsigned int*)&Hb[w][c][16 + 4 * g + 2] = pack2((h1v[2]-mu)*inv, (h1v[3]-mu)*inv);
            }
            lds_fence();
            const short8 bhf = *(const short8*)&Hb[w][c][8 * g];

            // ---- stage 2 ----
            f32x4 d0, d1;
#pragma unroll
            for (int r = 0; r < 4; ++r) { d0[r] = bs2[0][r]; d1[r] = bs2[1][r]; }
            d0 = MFMA16(aw[0], bhf, d0);
            d1 = MFMA16(aw[1], bhf, d1);
            float h20[4], h21[4];
#pragma unroll
            for (int r = 0; r < 4; ++r) { h20[r] = silu_f(d0[r]); h21[r] = silu_f(d1[r]); }

            lds_fence();
            *(unsigned int*)&Hb[w][c][4 * g]     = pack2(h20[0], h20[1]);
            *(unsigned int*)&Hb[w][c][4 * g + 2] = pack2(h20[2], h20[3]);
            if (g < 2) {
                *(unsigned int*)&Hb[w][c][16 + 4 * g]     = pack2(h21[0], h21[1]);
                *(unsigned int*)&Hb[w][c][16 + 4 * g + 2] = pack2(h21[2], h21[3]);
            }
            lds_fence();
            const short8 bh2 = *(const short8*)&Hb[w][c][8 * g];

            // ---- experts hidden: 4 M-tiles over 60-feature concat ----
            f32x4 ec[4];
#pragma unroll
            for (int t = 0; t < 4; ++t) {
#pragma unroll
                for (int r = 0; r < 4; ++r) ec[t][r] = bse[t][r];
                ec[t] = MFMA16(ae[t], bh2, ec[t]);
            }
            lds_fence();
#pragma unroll
            for (int t = 0; t < 4; ++t) {  // invalid feats (>=60) are exactly 0 -> safe pad
                *(unsigned int*)&Eb[w][c][16 * t + 4 * g]     = pack2(silu_f(ec[t][0]), silu_f(ec[t][1]));
                *(unsigned int*)&Eb[w][c][16 * t + 4 * g + 2] = pack2(silu_f(ec[t][2]), silu_f(ec[t][3]));
            }
            lds_fence();
            const short8 bea = *(const short8*)&Eb[w][c][8 * g];
            const short8 beb = *(const short8*)&Eb[w][c][32 + 8 * g];

            // ---- expert outputs (block-diag We2, osc+be2 folded) ----
            f32x4 co;
#pragma unroll
            for (int r = 0; r < 4; ++r) co[r] = bso[r];
            co = MFMA16(ao[0], bea, co);
            co = MFMA16(ao[1], beb, co);

            // ---- final gather per row via Fb ----
            lds_fence();
#pragma unroll
            for (int r = 0; r < 4; ++r) {
                const int m = 4 * g + r;
                if (m < 9) Fb[w][c][m] = co[r];
            }
            if (g == 0) {
#pragma unroll
                for (int r = 0; r < 3; ++r) Fb[w][c][9 + r] = cg[r];
            }
            if (g == 2) {
#pragma unroll
                for (int r = 0; r < 3; ++r) Fb[w][c][12 + r] = c2[r];  // lin (bh included)
            }
            lds_fence();
            const float4 f0 = *(const float4*)&Fb[w][c][0];
            const float4 f1 = *(const float4*)&Fb[w][c][4];
            const float4 f2 = *(const float4*)&Fb[w][c][8];
            const float4 f3 = *(const float4*)&Fb[w][c][12];

            const float lg0 = f2.y, lg1 = f2.z, lg2 = f2.w;
            const float mx = fmaxf(lg0, fmaxf(lg1, lg2));
            const float e0 = fexp2((lg0 - mx) * LOG2E);
            const float e1 = fexp2((lg1 - mx) * LOG2E);
            const float e2 = fexp2((lg2 - mx) * LOG2E);
            const float rs = frcp(e0 + e1 + e2);
            const float gw0 = e0 * rs, gw1 = e1 * rs, gw2 = e2 * rs;
            // eo[m=3e+o]: m0..3=f0, m4..7=f1, m8=f2.x ; lin = f3.xyz
            const float o0 = f3.x + gw0 * f0.x + gw1 * f0.w + gw2 * f1.z;
            const float o1 = f3.y + gw0 * f0.y + gw1 * f1.x + gw2 * f1.w;
            const float o2 = f3.z + gw0 * f0.z + gw1 * f1.y + gw2 * f2.x;

            if (g == 0) {
                float* op = out + row * 3;
                op[0] = o0; op[1] = o1; op[2] = o2;
            }
        }
    }
}

extern "C" void kernel_launch(void* const* d_in, const int* in_sizes, int n_in,
                              void* d_out, int out_size, void* d_ws, size_t ws_size,
                              hipStream_t stream) {
    const float* x   = (const float*)d_in[0];
    const float* W1  = (const float*)d_in[1];
    const float* b1  = (const float*)d_in[2];
    const float* lng = (const float*)d_in[3];
    const float* lnb = (const float*)d_in[4];
    const float* W2  = (const float*)d_in[5];
    const float* b2  = (const float*)d_in[6];
    const float* Wg1 = (const float*)d_in[7];
    const float* bg1 = (const float*)d_in[8];
    const float* Wg2 = (const float*)d_in[9];
    const float* bg2 = (const float*)d_in[10];
    const float* We1 = (const float*)d_in[11];
    const float* be1 = (const float*)d_in[12];
    const float* We2 = (const float*)d_in[13];
    const float* be2 = (const float*)d_in[14];
    const float* Wh  = (const float*)d_in[15];
    const float* bh  = (const float*)d_in[16];
    const float* osc = (const float*)d_in[17];
    float* out = (float*)d_out;

    const int B = in_sizes[0] / 64;
    moe_mfma_kernel<<<dim3(1024), dim3(256), 0, stream>>>(
        x, W1, b1, lng, lnb, W2, b2, Wg1, bg1, Wg2, bg2,
        We1, be1, We2, be2, Wh, bh, osc, out, B);
}

// Round 3
// 181.420 us; speedup vs baseline: 1.1000x; 1.0916x over previous
//
#include <hip/hip_runtime.h>

typedef __attribute__((ext_vector_type(8))) short short8;
typedef __attribute__((ext_vector_type(4))) short short4v;
typedef __attribute__((ext_vector_type(4))) float f32x4;

#define LOG2E 1.44269504088896340736f

__device__ __forceinline__ float fexp2(float v){ return __builtin_amdgcn_exp2f(v); }
__device__ __forceinline__ float frcp(float v){ return __builtin_amdgcn_rcpf(v); }
__device__ __forceinline__ float silu_f(float v){ return v * frcp(1.0f + fexp2(-v*LOG2E)); }
__device__ __forceinline__ float tanh_f(float v){ return 2.0f*frcp(1.0f+fexp2(-2.0f*LOG2E*v)) - 1.0f; }

__device__ __forceinline__ unsigned short f2bf(float f){
    unsigned int u = __float_as_uint(f);
    u = (u + 0x7FFFu + ((u>>16)&1u)) >> 16;
    return (unsigned short)u;
}
// v_cvt_pk_bf16_f32: lo16 = bf16(a), hi16 = bf16(b)
__device__ __forceinline__ unsigned int cvt_pk(float a, float b){
    unsigned int r;
    asm("v_cvt_pk_bf16_f32 %0, %1, %2" : "=v"(r) : "v"(a), "v"(b));
    return r;
}
__device__ __forceinline__ short4v mk4(unsigned int u0, unsigned int u1){
    union { unsigned int u[2]; short4v s; } cv;
    cv.u[0]=u0; cv.u[1]=u1; return cv.s;
}
__device__ __forceinline__ short8 mk8(unsigned int a, unsigned int b, unsigned int c, unsigned int d){
    union { unsigned int u[4]; short8 s; } cv;
    cv.u[0]=a; cv.u[1]=b; cv.u[2]=c; cv.u[3]=d; return cv.s;
}

#define MFMA32(a,b,c) __builtin_amdgcn_mfma_f32_16x16x32_bf16(a,b,c,0,0,0)
#define MFMA16(a,b,c) __builtin_amdgcn_mfma_f32_16x16x16bf16_1k(a,b,c,0,0,0)

// Layouts (validated round 2 for 16x16x32; 16x16x16 is the same pattern at K/2):
//  A frag: m=lane&15,  k = KW*(lane>>4)+e   (KW=8 for x32, 4 for x16)
//  B frag: n=lane&15,  k = KW*(lane>>4)+e
//  C frag: n=lane&15,  m = 4*(lane>>4)+r
// => C of one stage feeds B of a 16x16x16 stage with NO cross-lane movement.

__global__ __launch_bounds__(256, 3) void moe_mfma2_kernel(
    const float* __restrict__ x,
    const float* __restrict__ W1,  const float* __restrict__ b1,
    const float* __restrict__ lng, const float* __restrict__ lnb,
    const float* __restrict__ W2,  const float* __restrict__ b2,
    const float* __restrict__ Wg1, const float* __restrict__ bg1,
    const float* __restrict__ Wg2, const float* __restrict__ bg2,
    const float* __restrict__ We1, const float* __restrict__ be1,
    const float* __restrict__ We2, const float* __restrict__ be2,
    const float* __restrict__ Wh,  const float* __restrict__ bh,
    const float* __restrict__ osc,
    float* __restrict__ out, int B, int niter)
{
    const int tid  = threadIdx.x;
    const int w    = tid >> 6;
    const int lane = tid & 63;
    const int c    = lane & 15;   // batch row within group / A-row m
    const int g    = lane >> 4;   // lane group 0..3

    const long long stride = (long long)gridDim.x * 64;
    long long row0 = (long long)blockIdx.x * 64 + w * 16;

    // ---- prefetch iter 0 (issued before the long init; latency hidden) ----
    float4 pf0, pf1, pf2, pf3;
    if (row0 < B) {
        const float* xp = x + (row0 + c) * 64 + 8 * g;
        pf0 = *(const float4*)(xp);
        pf1 = *(const float4*)(xp + 4);
        pf2 = *(const float4*)(xp + 32);
        pf3 = *(const float4*)(xp + 36);
    }

    // ================= one-time weight/bias fragment init =================
    // stage1 concat features f: [0,24)=W1, [24,40)=Wg1, [40,43)=Wh, pad to 48
    short8 a1[3][2];
#pragma unroll
    for (int t = 0; t < 3; ++t) {
        const int f = 16 * t + c;
#pragma unroll
        for (int s = 0; s < 2; ++s) {
            short8 r;
#pragma unroll
            for (int e = 0; e < 8; ++e) {
                const int k = 32 * s + 8 * g + e;
                float v = 0.0f;
                if (f < 24)      v = W1[k * 24 + f];
                else if (f < 40) v = Wg1[k * 16 + (f - 24)];
                else if (f < 43) v = Wh[k * 3 + (f - 40)];
                r[e] = (short)f2bf(v);
            }
            a1[t][s] = r;
        }
    }
    // W2 (lng folded into rows), K=24 padded to 32; bias b2' in k==24 slot
    short4v aw[2][2];
#pragma unroll
    for (int t = 0; t < 2; ++t) {
        const int f = 16 * t + c;
        float bfold = 0.0f;
        if (f < 24) {
            bfold = b2[f];
            for (int k = 0; k < 24; ++k) bfold += lnb[k] * W2[k * 24 + f];
        }
#pragma unroll
        for (int s = 0; s < 2; ++s) {
            short4v r;
#pragma unroll
            for (int e = 0; e < 4; ++e) {
                const int k = 16 * s + 4 * g + e;
                float v = (f < 24 && k < 24) ? lng[k] * W2[k * 24 + f] : 0.0f;
                if (s == 1 && g == 2 && e == 0) v = bfold;   // k==24 bias slot
                r[e] = (short)f2bf(v);
            }
            aw[t][s] = r;
        }
    }
    // experts hidden concat m=20*ei+j in [0,60), K=24 pad 32; be1 in k==24 slot
    short4v ae[4][2];
#pragma unroll
    for (int t = 0; t < 4; ++t) {
        const int f  = 16 * t + c;
        const int fc = (f < 60) ? f : 0;
        const int ei = fc / 20, j = fc % 20;
        const float bias = (f < 60) ? be1[f] : 0.0f;
#pragma unroll
        for (int s = 0; s < 2; ++s) {
            short4v r;
#pragma unroll
            for (int e = 0; e < 4; ++e) {
                const int k = 16 * s + 4 * g + e;
                float v = (f < 60 && k < 24) ? We1[(ei * 24 + k) * 20 + j] : 0.0f;
                if (s == 1 && g == 2 && e == 0) v = bias;    // k==24 bias slot
                r[e] = (short)f2bf(v);
            }
            ae[t][s] = r;
        }
    }
    // We2 block-diag, osc folded, K=60 pad 64; be2*osc in k==60 slot
    short4v ao[4];
    {
        const int f  = c;
        const int fc = (f < 9) ? f : 0;
        const int ei = fc / 3, o = fc % 3;
        const float oscv = (f < 9) ? osc[o] : 0.0f;
        const float bias = (f < 9) ? be2[f] * oscv : 0.0f;
#pragma unroll
        for (int s = 0; s < 4; ++s) {
            short4v r;
#pragma unroll
            for (int e = 0; e < 4; ++e) {
                const int k  = 16 * s + 4 * g + e;
                const int ke = k - 20 * ei;
                const int kec = (ke >= 0 && ke < 20) ? ke : 0;
                float v = (f < 9 && ke >= 0 && ke < 20) ? We2[(ei * 20 + kec) * 3 + o] * oscv : 0.0f;
                if (s == 3 && g == 3 && e == 0) v = bias;    // k==60 bias slot
                r[e] = (short)f2bf(v);
            }
            ao[s] = r;
        }
    }
    // gate Wg2: K=16 exact
    short4v ag;
#pragma unroll
    for (int e = 0; e < 4; ++e) {
        const int k = 4 * g + e;
        float v = (c < 3) ? Wg2[k * 3 + c] : 0.0f;
        ag[e] = (short)f2bf(v);
    }
    // stage1 biases (K=64 exact, no pad slot available) + gate bias
    float bs1[3][4];
#pragma unroll
    for (int t = 0; t < 3; ++t)
#pragma unroll
    for (int r = 0; r < 4; ++r) {
        const int m = 16 * t + 4 * g + r;
        float v = 0.0f;
        if (m < 24)      v = b1[m];
        else if (m < 40) v = bg1[m - 24];
        else if (m < 43) v = bh[m - 40];
        bs1[t][r] = v;
    }
    float bsg[4];
#pragma unroll
    for (int r = 0; r < 4; ++r) { const int m = 4 * g + r; bsg[r] = (m < 3) ? bg2[m] : 0.0f; }

    const unsigned int ONEBF = 0x00003F80u;  // lo half = bf16(1.0)

    // ================= main loop: one 16-row group per wave per iter =================
    for (int it = 0; it < niter; ++it) {
        if (row0 >= B) break;
        const float4 q0 = pf0, q1 = pf1, q2 = pf2, q3 = pf3;
        const long long nrow0 = row0 + stride;
        if (it + 1 < niter && nrow0 < B) {
            const float* np = x + (nrow0 + c) * 64 + 8 * g;
            pf0 = *(const float4*)(np);
            pf1 = *(const float4*)(np + 4);
            pf2 = *(const float4*)(np + 32);
            pf3 = *(const float4*)(np + 36);
        }

        const short8 bx0 = mk8(cvt_pk(q0.x,q0.y), cvt_pk(q0.z,q0.w),
                               cvt_pk(q1.x,q1.y), cvt_pk(q1.z,q1.w));
        const short8 bx1 = mk8(cvt_pk(q2.x,q2.y), cvt_pk(q2.z,q2.w),
                               cvt_pk(q3.x,q3.y), cvt_pk(q3.z,q3.w));

        // ---- stage 1: 3 M-tiles x K=64 ----
        f32x4 c0 = {bs1[0][0], bs1[0][1], bs1[0][2], bs1[0][3]};
        f32x4 c1 = {bs1[1][0], bs1[1][1], bs1[1][2], bs1[1][3]};
        f32x4 c2 = {bs1[2][0], bs1[2][1], bs1[2][2], bs1[2][3]};
        c0 = MFMA32(a1[0][0], bx0, c0); c0 = MFMA32(a1[0][1], bx1, c0);
        c1 = MFMA32(a1[1][0], bx0, c1); c1 = MFMA32(a1[1][1], bx1, c1);
        c2 = MFMA32(a1[2][0], bx0, c2); c2 = MFMA32(a1[2][1], bx1, c2);

        // ---- gate: send tanh of the tile this lane owns; receive from lane^32 ----
        // dest g needs gate feats k=4g..4g+3 = concat m=24+4g.. -> held by lane^32
        const f32x4 ts = (g < 2) ? c2 : c1;
        const unsigned int gs0 = cvt_pk(tanh_f(ts[0]), tanh_f(ts[1]));
        const unsigned int gs1 = cvt_pk(tanh_f(ts[2]), tanh_f(ts[3]));
        const unsigned int gr0 = (unsigned int)__shfl_xor((int)gs0, 32, 64);
        const unsigned int gr1 = (unsigned int)__shfl_xor((int)gs1, 32, 64);
        f32x4 cg = {bsg[0], bsg[1], bsg[2], bsg[3]};
        cg = MFMA16(ag, mk4(gr0, gr1), cg);

        // ---- silu + LayerNorm (lng/lnb folded into aw / k==24 slot) ----
        const float h00=silu_f(c0[0]), h01=silu_f(c0[1]), h02=silu_f(c0[2]), h03=silu_f(c0[3]);
        const float h10=silu_f(c1[0]), h11=silu_f(c1[1]), h12=silu_f(c1[2]), h13=silu_f(c1[3]);
        float S = h00+h01+h02+h03;
        float Q = h00*h00+h01*h01+h02*h02+h03*h03;
        if (g < 2) { S += h10+h11+h12+h13; Q += h10*h10+h11*h11+h12*h12+h13*h13; }
        S += __shfl_xor(S, 16, 64); S += __shfl_xor(S, 32, 64);
        Q += __shfl_xor(Q, 16, 64); Q += __shfl_xor(Q, 32, 64);
        const float mu = S * (1.0f/24.0f);
        float var = Q * (1.0f/24.0f) - mu*mu; var = fmaxf(var, 0.0f);
        const float inv = __builtin_amdgcn_rsqf(var + 1e-5f);

        const short4v B0 = mk4(cvt_pk((h00-mu)*inv, (h01-mu)*inv),
                               cvt_pk((h02-mu)*inv, (h03-mu)*inv));
        const short4v B1 = (g < 2) ? mk4(cvt_pk((h10-mu)*inv, (h11-mu)*inv),
                                         cvt_pk((h12-mu)*inv, (h13-mu)*inv))
                         : ((g == 2) ? mk4(ONEBF, 0u) : mk4(0u, 0u));

        // ---- stage 2 (C init 0; bias rides k==24 slot) ----
        f32x4 d0 = {0.f,0.f,0.f,0.f}, d1 = {0.f,0.f,0.f,0.f};
        d0 = MFMA16(aw[0][0], B0, d0); d0 = MFMA16(aw[0][1], B1, d0);
        d1 = MFMA16(aw[1][0], B0, d1); d1 = MFMA16(aw[1][1], B1, d1);
        const float j00=silu_f(d0[0]), j01=silu_f(d0[1]), j02=silu_f(d0[2]), j03=silu_f(d0[3]);
        const float j10=silu_f(d1[0]), j11=silu_f(d1[1]), j12=silu_f(d1[2]), j13=silu_f(d1[3]);
        const short4v E0 = mk4(cvt_pk(j00,j01), cvt_pk(j02,j03));
        const short4v E1 = (g < 2) ? mk4(cvt_pk(j10,j11), cvt_pk(j12,j13))
                         : ((g == 2) ? mk4(ONEBF, 0u) : mk4(0u, 0u));

        // ---- experts hidden: 60-feature concat, 4 M-tiles ----
        f32x4 ec0={0.f,0.f,0.f,0.f}, ec1={0.f,0.f,0.f,0.f}, ec2={0.f,0.f,0.f,0.f}, ec3={0.f,0.f,0.f,0.f};
        ec0 = MFMA16(ae[0][0], E0, ec0); ec0 = MFMA16(ae[0][1], E1, ec0);
        ec1 = MFMA16(ae[1][0], E0, ec1); ec1 = MFMA16(ae[1][1], E1, ec1);
        ec2 = MFMA16(ae[2][0], E0, ec2); ec2 = MFMA16(ae[2][1], E1, ec2);
        ec3 = MFMA16(ae[3][0], E0, ec3); ec3 = MFMA16(ae[3][1], E1, ec3);

        // ---- expert outputs: K=64 over silu(expert hidden); bias rides k==60 ----
        const short4v F0 = mk4(cvt_pk(silu_f(ec0[0]),silu_f(ec0[1])), cvt_pk(silu_f(ec0[2]),silu_f(ec0[3])));
        const short4v F1 = mk4(cvt_pk(silu_f(ec1[0]),silu_f(ec1[1])), cvt_pk(silu_f(ec1[2]),silu_f(ec1[3])));
        const short4v F2 = mk4(cvt_pk(silu_f(ec2[0]),silu_f(ec2[1])), cvt_pk(silu_f(ec2[2]),silu_f(ec2[3])));
        const short4v F3 = (g == 3) ? mk4(ONEBF, 0u)
                         : mk4(cvt_pk(silu_f(ec3[0]),silu_f(ec3[1])), cvt_pk(silu_f(ec3[2]),silu_f(ec3[3])));
        f32x4 co = {0.f,0.f,0.f,0.f};
        co = MFMA16(ao[0], F0, co); co = MFMA16(ao[1], F1, co);
        co = MFMA16(ao[2], F2, co); co = MFMA16(ao[3], F3, co);

        // ---- combine: broadcast logits from group 0, reduce moe partials ----
        const float l0 = __shfl(cg[0], c, 64);
        const float l1 = __shfl(cg[1], c, 64);
        const float l2 = __shfl(cg[2], c, 64);
        const float mx = fmaxf(l0, fmaxf(l1, l2));
        const float x0 = fexp2((l0-mx)*LOG2E), x1 = fexp2((l1-mx)*LOG2E), x2 = fexp2((l2-mx)*LOG2E);
        const float rs = frcp(x0 + x1 + x2);
        const float gw0 = x0*rs, gw1 = x1*rs, gw2 = x2*rs;

        float p0 = 0.f, p1 = 0.f, p2 = 0.f;      // eo[m=4g+r], o=m%3, e=m/3
        if (g == 0)      { p0 = gw0*co[0] + gw1*co[3]; p1 = gw0*co[1]; p2 = gw0*co[2]; }
        else if (g == 1) { p1 = gw1*co[0] + gw2*co[3]; p2 = gw1*co[1]; p0 = gw2*co[2]; }
        else if (g == 2) { p2 = gw2*co[0]; }
        p0 += __shfl_xor(p0, 16, 64); p0 += __shfl_xor(p0, 32, 64);
        p1 += __shfl_xor(p1, 16, 64); p1 += __shfl_xor(p1, 32, 64);
        p2 += __shfl_xor(p2, 16, 64); p2 += __shfl_xor(p2, 32, 64);

        // lin (bh folded) lives in c2 regs of group 2
        const float lin0 = __shfl(c2[0], c + 32, 64);
        const float lin1 = __shfl(c2[1], c + 32, 64);
        const float lin2 = __shfl(c2[2], c + 32, 64);

        if (g < 3) {   // 48 lanes write 48 contiguous dwords (16 rows x 3)
            const float v = (g == 0) ? (lin0 + p0) : ((g == 1) ? (lin1 + p1) : (lin2 + p2));
            out[row0 * 3 + c * 3 + g] = v;
        }

        row0 = nrow0;
    }
}

extern "C" void kernel_launch(void* const* d_in, const int* in_sizes, int n_in,
                              void* d_out, int out_size, void* d_ws, size_t ws_size,
                              hipStream_t stream) {
    const float* x   = (const float*)d_in[0];
    const float* W1  = (const float*)d_in[1];
    const float* b1  = (const float*)d_in[2];
    const float* lng = (const float*)d_in[3];
    const float* lnb = (const float*)d_in[4];
    const float* W2  = (const float*)d_in[5];
    const float* b2  = (const float*)d_in[6];
    const float* Wg1 = (const float*)d_in[7];
    const float* bg1 = (const float*)d_in[8];
    const float* Wg2 = (const float*)d_in[9];
    const float* bg2 = (const float*)d_in[10];
    const float* We1 = (const float*)d_in[11];
    const float* be1 = (const float*)d_in[12];
    const float* We2 = (const float*)d_in[13];
    const float* be2 = (const float*)d_in[14];
    const float* Wh  = (const float*)d_in[15];
    const float* bh  = (const float*)d_in[16];
    const float* osc = (const float*)d_in[17];
    float* out = (float*)d_out;

    const int B = in_sizes[0] / 64;
    const int G = 4096;
    const long long per = (long long)G * 64;
    const int niter = (int)((B + per - 1) / per);
    moe_mfma2_kernel<<<dim3(G), dim3(256), 0, stream>>>(
        x, W1, b1, lng, lnb, W2, b2, Wg1, bg1, Wg2, bg2,
        We1, be1, We2, be2, Wh, bh, osc, out, B, niter);
}